// Round 6
// baseline (292.980 us; speedup 1.0000x reference)
//
#include <hip/hip_runtime.h>

typedef short bfrag __attribute__((ext_vector_type(8)));   // 8 x bf16 (4 VGPRs)
typedef float facc  __attribute__((ext_vector_type(4)));   // MFMA accumulator
typedef unsigned short u16;
typedef unsigned int   u32;

#define LOG2E 1.4426950408889634f
#define K2E   (2.0f*LOG2E)
#define MFMA(A,B,C) __builtin_amdgcn_mfma_f32_16x16x32_bf16((A),(B),(C),0,0,0)

// ---- LDS element offsets (u16 units) ----
// AS/VS/LS: softmax(a/v/l) [16][136]; after P3-cc1 they die and are reused as
//           uni/bim/tri fusion segments for P4.
#define AS_E 0
#define VS_E 2176
#define LS_E 4352
#define AV_E 6528         // a_v [16][136]
#define AL_E 8704         // a_l
#define VL_E 10880        // v_l
// HH region (6912 elems): time-multiplexed H3 (3x[16][72]) -> U=exp(G) (3x[16][136])
//                         -> H6 (6x[16][72]) -> ll scratch (2x[16][72])
#define HH_E 13056
#define DSCR_B 39936      // dot scratch: f32[16][9]  (576 B) — MFMA-diag atomics
#define NSCR_B 40512      // n scratch:   f32[16][6]  (384 B) — n1 (0..2) then n2 (0..5)
#define SM_BYTES 40896    // rounds to 40960; 4 blocks/CU exactly

__device__ __forceinline__ float ex2(float x){ return __builtin_amdgcn_exp2f(x); }
__device__ __forceinline__ float rcpf_(float x){ return __builtin_amdgcn_rcpf(x); }
// tanh where y = (x)*2*LOG2E is already formed (bias pre-scaled by caller)
__device__ __forceinline__ float ftanh_pre(float y){ return 1.0f - 2.0f*rcpf_(ex2(y) + 1.0f); }
__device__ __forceinline__ u16 f2b(float x){ return (u16)((__float_as_uint(x) + 0x8000u)>>16); }
__device__ __forceinline__ u32 pk2(float x0, float x1){
  return __builtin_amdgcn_perm(__float_as_uint(x1)+0x8000u, __float_as_uint(x0)+0x8000u, 0x07060302u);
}
// 16-lane reductions via DPP row_ror (VALU pipe, not LDS)
template<int N>
__device__ __forceinline__ float ror16f(float v){
  return __int_as_float(__builtin_amdgcn_update_dpp(0, __float_as_int(v), 0x120|N, 0xF, 0xF, false));
}
__device__ __forceinline__ float rsum16(float v){
  v += ror16f<8>(v); v += ror16f<4>(v); v += ror16f<2>(v); v += ror16f<1>(v); return v;
}
__device__ __forceinline__ void st4b(u16* p, float x0,float x1,float x2,float x3){
  *(uint2*)p = make_uint2(pk2(x0,x1), pk2(x2,x3));
}

// ---- prep: transpose all weight matrices to bf16 [n][k] blobs in ws ----
__global__ void prep_weights(const float* __restrict__ gf_w1, const float* __restrict__ gf_w2,
                             const float* __restrict__ gf2_w1, const float* __restrict__ gf2_w2,
                             const float* __restrict__ ll_w1, const float* __restrict__ ll_w2,
                             const float* __restrict__ ll_w3, u16* __restrict__ blob)
{
  u32 i = blockIdx.x*256u + threadIdx.x;
  if (i >= 86016u) return;
  u32 off, K, N; const float* src;
  if      (i < 16384u){ off=0u;     K=256u; N=64u;  src=gf_w1; }
  else if (i < 24576u){ off=16384u; K=64u;  N=128u; src=gf_w2; }
  else if (i < 40960u){ off=24576u; K=256u; N=64u;  src=gf2_w1; }
  else if (i < 49152u){ off=40960u; K=64u;  N=128u; src=gf2_w2; }
  else if (i < 73728u){ off=49152u; K=384u; N=64u;  src=ll_w1; }
  else if (i < 77824u){ off=73728u; K=64u;  N=64u;  src=ll_w2; }
  else               { off=77824u; K=64u;  N=128u; src=ll_w3; }
  u32 li = i - off, n = li / K, k = li - n*K;
  blob[i] = f2b(src[k*N + n]);   // wt[n][k] = w[k][n]
}

__global__ __launch_bounds__(256) __attribute__((amdgpu_waves_per_eu(4,4)))
void fused_graph(
    const float* __restrict__ Lg, const float* __restrict__ Ag, const float* __restrict__ Vg,
    const float* __restrict__ att_w, const float* __restrict__ att_b,
    const float* __restrict__ gf_b1, const float* __restrict__ gf_b2,
    const float* __restrict__ gf2_b1, const float* __restrict__ gf2_b2,
    const float* __restrict__ ll_b1, const float* __restrict__ ll_b2, const float* __restrict__ ll_b3,
    const u16* __restrict__ wb, float* __restrict__ out)
{
  __shared__ alignas(16) char sm[SM_BYTES];
  u16* smu = (u16*)sm;
  float* dscr = (float*)(sm + DSCR_B);   // [16][9]
  float* nscr = (float*)(sm + NSCR_B);   // [16][6]

  const int tid = threadIdx.x;
  const int lane = tid & 63;
  const int w = tid >> 6;        // wave 0..3
  const int m = lane & 15;       // MFMA row(A)/col(B)/col(C)
  const int q = lane >> 4;       // quad
  const int er = tid >> 4;       // elementwise row 0..15
  const int ep = tid & 15;       // elementwise lane-in-row
  const int row0 = blockIdx.x << 4;
  const int ka = w*32 + q*8;     // this wave's K-chunk offset for dot-MFMAs
  const bool diag = (q == (m>>2));  // lane holds diagonal elem C[m][m] in c[m&3]

  if (tid < 144) dscr[tid] = 0.0f;   // zero dot scratch

  // ================= P0: attention scalars, unimodal(->regs), softmaxes =================
  float sa, sv, sl;
  u32 uni_pk[4];
  {
    const int gb = (row0 + er)*128 + ep*4;
    facc A0 = *(const facc*)(Ag+gb), A1 = *(const facc*)(Ag+gb+64);
    facc V0 = *(const facc*)(Vg+gb), V1 = *(const facc*)(Vg+gb+64);
    facc L0 = *(const facc*)(Lg+gb), L1 = *(const facc*)(Lg+gb+64);
    facc W0 = *(const facc*)(att_w+ep*4), W1 = *(const facc*)(att_w+ep*4+64);
    float abk = att_b[0]*K2E;
    float pa=0.f,pv=0.f,pl=0.f;
    #pragma unroll
    for (int i=0;i<4;i++){ pa += A0[i]*W0[i]+A1[i]*W1[i]; pv += V0[i]*W0[i]+V1[i]*W1[i]; pl += L0[i]*W0[i]+L1[i]*W1[i]; }
    sa = ftanh_pre(fmaf(rsum16(pa),K2E,abk));
    sv = ftanh_pre(fmaf(rsum16(pv),K2E,abk));
    sl = ftanh_pre(fmaf(rsum16(pl),K2E,abk));
    {
      const float th = 1.0f/3.0f;
      uni_pk[0] = pk2((sa*A0[0]+sv*V0[0]+sl*L0[0])*th, (sa*A0[1]+sv*V0[1]+sl*L0[1])*th);
      uni_pk[1] = pk2((sa*A0[2]+sv*V0[2]+sl*L0[2])*th, (sa*A0[3]+sv*V0[3]+sl*L0[3])*th);
      uni_pk[2] = pk2((sa*A1[0]+sv*V1[0]+sl*L1[0])*th, (sa*A1[1]+sv*V1[1]+sl*L1[1])*th);
      uni_pk[3] = pk2((sa*A1[2]+sv*V1[2]+sl*L1[2])*th, (sa*A1[3]+sv*V1[3]+sl*L1[3])*th);
    }
    // softmaxes without max-subtraction (inputs N(0,1), fp32 exp2 range safe)
    #define SMAX(X0,X1,OFFE) { \
      float s_=0.f; \
      _Pragma("unroll") for (int i=0;i<4;i++){ X0[i]=ex2(X0[i]*LOG2E); X1[i]=ex2(X1[i]*LOG2E); s_+=X0[i]+X1[i]; } \
      s_ = rsum16(s_); float rs_ = rcpf_(s_); \
      _Pragma("unroll") for (int i=0;i<4;i++){ X0[i]*=rs_; X1[i]*=rs_; } \
      u16* dp_ = smu + (OFFE) + er*136 + ep*4; \
      st4b(dp_, X0[0],X0[1],X0[2],X0[3]); st4b(dp_+64, X1[0],X1[1],X1[2],X1[3]); }
    SMAX(A0,A1,AS_E)
    SMAX(V0,V1,VS_E)
    SMAX(L0,L1,LS_E)
  } // all f32 input state dies here
  __syncthreads();   // (1) softmaxes ready, dscr zeroed

  // ---- P0b: modality dots via MFMA diag: dav,dal,dvl -> dscr[.][0..2] ----
  {
    bfrag fA = *(const bfrag*)(smu + AS_E + m*136 + ka);
    bfrag fV = *(const bfrag*)(smu + VS_E + m*136 + ka);
    bfrag fL = *(const bfrag*)(smu + LS_E + m*136 + ka);
    facc z = {0,0,0,0};
    facc cav = MFMA(fA, fV, z);
    facc cal = MFMA(fA, fL, z);
    facc cvl = MFMA(fV, fL, z);
    if (diag){
      int r = m&3;
      atomicAdd(&dscr[m*9+0], cav[r]);
      atomicAdd(&dscr[m*9+1], cal[r]);
      atomicAdd(&dscr[m*9+2], cvl[r]);
    }
  }

  // ================= P1: gf on 3 pairs =================
  const u16* g1t = wb;            // [64][256]
  const u16* g2t = wb + 16384;    // [128][64]
  bfrag B1[8];
  #pragma unroll
  for (int s=0;s<8;s++) B1[s] = *(const bfrag*)(g1t + (w*16+m)*256 + s*32 + q*8);
  bfrag B2[2][2];
  #pragma unroll
  for (int t=0;t<2;t++){
    #pragma unroll
    for (int s=0;s<2;s++) B2[t][s] = *(const bfrag*)(g2t + ((w+4*t)*16+m)*64 + s*32 + q*8);
  }
  facc acc0={0,0,0,0}, acc1={0,0,0,0}, acc2={0,0,0,0};
  #pragma unroll
  for (int s=0;s<8;s++){
    int k = s*32 + q*8, ko = k & 127; bool hi = (k >= 128);
    // pair0=(a,v): lo AS, hi VS ; pair1=(a,l): lo AS, hi LS ; pair2=(v,l): lo VS, hi LS
    bfrag fX = *(const bfrag*)(smu + (hi? VS_E:AS_E) + m*136 + ko);
    bfrag fY = *(const bfrag*)(smu + (hi? LS_E:VS_E) + m*136 + ko);
    acc0 = MFMA(fX, B1[s], acc0);
    acc1 = MFMA(hi? fY : fX, B1[s], acc1);
    acc2 = MFMA(fY, B1[s], acc2);
  }
  { // leaky_relu -> H3 @ HH_E (stride 72)
    float b1v = gf_b1[w*16+m];
    #pragma unroll
    for (int r=0;r<4;r++){
      int rr = q*4+r;
      float h0 = acc0[r]+b1v; h0 = fmaxf(h0, 0.2f*h0);
      float h1 = acc1[r]+b1v; h1 = fmaxf(h1, 0.2f*h1);
      float h2 = acc2[r]+b1v; h2 = fmaxf(h2, 0.2f*h2);
      smu[HH_E + 0*1152 + rr*72 + w*16+m] = f2b(h0);
      smu[HH_E + 1*1152 + rr*72 + w*16+m] = f2b(h1);
      smu[HH_E + 2*1152 + rr*72 + w*16+m] = f2b(h2);
    }
  }
  __syncthreads();   // (2) H3 ready; P0b dot atomics complete

  float sav=0.f, sal=0.f, svl=0.f;   // meaningful in ep==0 threads only
  if (ep==0){
    float dav=dscr[er*9+0], dal=dscr[er*9+1], dvl=dscr[er*9+2];
    sav = (sa+sv)*rcpf_(dav+0.5f);
    sal = (sa+sl)*rcpf_(dal+0.5f);
    svl = (sl+sv)*rcpf_(dvl+0.5f);
    float e0 = ex2(sav*LOG2E), e1 = ex2(sal*LOG2E), e2 = ex2(svl*LOG2E);
    float rs = rcpf_(e0+e1+e2);
    nscr[er*6+0]=e0*rs; nscr[er*6+1]=e1*rs; nscr[er*6+2]=e2*rs;   // n1
    dscr[er*9+0]=0.f; dscr[er*9+1]=0.f; dscr[er*9+2]=0.f;         // re-zero for P2 dots
  }
  facc c2[3][2] = {{{0,0,0,0},{0,0,0,0}},{{0,0,0,0},{0,0,0,0}},{{0,0,0,0},{0,0,0,0}}};
  #pragma unroll
  for (int s=0;s<2;s++){
    int k = s*32 + q*8;
    #pragma unroll
    for (int p3=0;p3<3;p3++){
      bfrag Af = *(const bfrag*)(smu + HH_E + p3*1152 + m*72 + k);
      c2[p3][0] = MFMA(Af, B2[0][s], c2[p3][0]);
      c2[p3][1] = MFMA(Af, B2[1][s], c2[p3][1]);
    }
  }
  __syncthreads();   // (2b) H3 consumed — HH free for U=exp(G); n1 written
  float bim[2][4] = {{0,0,0,0},{0,0,0,0}};
  { // g = tanh(c2+b); store u = e^g; tt = tanh(n1*g); bim in regs
    float b2c0 = gf_b2[w*16+m]*K2E, b2c1 = gf_b2[(w+4)*16+m]*K2E;
    float nvc[4][3];
    #pragma unroll
    for (int r=0;r<4;r++){ int rr=q*4+r;
      nvc[r][0]=nscr[rr*6+0]*K2E; nvc[r][1]=nscr[rr*6+1]*K2E; nvc[r][2]=nscr[rr*6+2]*K2E; }
    #pragma unroll
    for (int p3=0;p3<3;p3++){
      #pragma unroll
      for (int t=0;t<2;t++){
        float bb = t? b2c1 : b2c0;
        int cc = (w+4*t)*16+m;
        #pragma unroll
        for (int r=0;r<4;r++){
          int rr=q*4+r;
          float g = ftanh_pre(fmaf(c2[p3][t][r], K2E, bb));
          float u = ex2(g*LOG2E);               // e^g in [0.37, 2.72]
          smu[HH_E + p3*2176 + rr*136 + cc] = f2b(u);
          float tt = ftanh_pre(g*nvc[r][p3]);
          smu[AV_E + p3*2176 + rr*136 + cc] = f2b(tt);
          bim[t][r] += tt;
        }
      }
    }
  }
  __syncthreads();   // (3) U + AV/AL/VL ready

  // ================= P2: 9 row-dots via MFMA diag (K split across waves) =================
  {
    bfrag fU0 = *(const bfrag*)(smu + HH_E + 0*2176 + m*136 + ka);
    bfrag fU1 = *(const bfrag*)(smu + HH_E + 1*2176 + m*136 + ka);
    bfrag fU2 = *(const bfrag*)(smu + HH_E + 2*2176 + m*136 + ka);
    bfrag fA  = *(const bfrag*)(smu + AS_E + m*136 + ka);
    bfrag fV  = *(const bfrag*)(smu + VS_E + m*136 + ka);
    bfrag fL  = *(const bfrag*)(smu + LS_E + m*136 + ka);
    const short one = 0x3F80;
    bfrag fOne = {one,one,one,one,one,one,one,one};
    facc z = {0,0,0,0};
    facc cS0 = MFMA(fU0, fOne, z);
    facc cS1 = MFMA(fU1, fOne, z);
    facc cS2 = MFMA(fU2, fOne, z);
    facc c01 = MFMA(fU0, fU1, z);
    facc c02 = MFMA(fU0, fU2, z);
    facc c12 = MFMA(fU1, fU2, z);
    facc c0l = MFMA(fU0, fL, z);
    facc c1v = MFMA(fU1, fV, z);
    facc c2a = MFMA(fU2, fA, z);
    if (diag){
      int r = m&3; float* dp = &dscr[m*9];
      atomicAdd(dp+0, cS0[r]); atomicAdd(dp+1, cS1[r]); atomicAdd(dp+2, cS2[r]);
      atomicAdd(dp+3, c01[r]); atomicAdd(dp+4, c02[r]); atomicAdd(dp+5, c12[r]);
      atomicAdd(dp+6, c0l[r]); atomicAdd(dp+7, c1v[r]); atomicAdd(dp+8, c2a[r]);
    }
  }

  // ================= P3: gf2 layer-1 on 6 pairs =================
  const u16* h1t = wb + 24576;
  const u16* h2t = wb + 40960;
  bfrag C1[8];
  #pragma unroll
  for (int s=0;s<8;s++) C1[s] = *(const bfrag*)(h1t + (w*16+m)*256 + s*32 + q*8);
  bfrag C2[2][2];
  #pragma unroll
  for (int t=0;t<2;t++){
    #pragma unroll
    for (int s=0;s<2;s++) C2[t][s] = *(const bfrag*)(h2t + ((w+4*t)*16+m)*64 + s*32 + q*8);
  }
  facc cc1[6];
  #pragma unroll
  for (int pr=0;pr<6;pr++){ facc z = {0,0,0,0}; cc1[pr] = z; }
  // pair sources: lo {AV,AV,VL,AV,AL,VL}, hi {VL,AL,AL,LS,VS,AS}
  #pragma unroll
  for (int s=0;s<8;s++){
    int k = s*32+q*8, ko = k&127; bool hi = (k>=128);
    const u16* b = smu + m*136 + ko;
    if (!hi){
      bfrag fAV=*(const bfrag*)(b+AV_E), fVL=*(const bfrag*)(b+VL_E), fAL=*(const bfrag*)(b+AL_E);
      cc1[0]=MFMA(fAV,C1[s],cc1[0]);
      cc1[1]=MFMA(fAV,C1[s],cc1[1]);
      cc1[2]=MFMA(fVL,C1[s],cc1[2]);
      cc1[3]=MFMA(fAV,C1[s],cc1[3]);
      cc1[4]=MFMA(fAL,C1[s],cc1[4]);
      cc1[5]=MFMA(fVL,C1[s],cc1[5]);
    } else {
      bfrag fVL=*(const bfrag*)(b+VL_E), fAL=*(const bfrag*)(b+AL_E);
      bfrag fLS=*(const bfrag*)(b+LS_E), fVS=*(const bfrag*)(b+VS_E), fAS=*(const bfrag*)(b+AS_E);
      cc1[0]=MFMA(fVL,C1[s],cc1[0]);
      cc1[1]=MFMA(fAL,C1[s],cc1[1]);
      cc1[2]=MFMA(fAL,C1[s],cc1[2]);
      cc1[3]=MFMA(fLS,C1[s],cc1[3]);
      cc1[4]=MFMA(fVS,C1[s],cc1[4]);
      cc1[5]=MFMA(fAS,C1[s],cc1[5]);
    }
  }
  __syncthreads();   // (4) U consumed (HH free for H6); P2 dot atomics complete

  { // H6 writes (overlay dead U region)
    float b1v = gf2_b1[w*16+m];
    #pragma unroll
    for (int pr=0;pr<6;pr++){
      #pragma unroll
      for (int r=0;r<4;r++){
        float h = cc1[pr][r]+b1v; h = fmaxf(h,0.2f*h);
        smu[HH_E + pr*1152 + (q*4+r)*72 + w*16+m] = f2b(h);
      }
    }
  }
  if (ep==0){ // combine dots -> n2 (overwrites dead n1 slots)
    float* dp = &dscr[er*9];
    float rs0=rcpf_(dp[0]), rs1=rcpf_(dp[1]), rs2=rcpf_(dp[2]);
    float x0 = (sav+svl)*rcpf_(fmaf(dp[4]*rs0, rs2, 0.5f));  // savvl
    float x1 = (sav+sal)*rcpf_(fmaf(dp[3]*rs0, rs1, 0.5f));  // saavl
    float x2 = (sal+svl)*rcpf_(fmaf(dp[5]*rs1, rs2, 0.5f));  // savll
    float x3 = (sav+sl )*rcpf_(fmaf(dp[6], rs0, 0.5f));      // savl
    float x4 = (sal+sv )*rcpf_(fmaf(dp[7], rs1, 0.5f));      // salv
    float x5 = (sa +svl)*rcpf_(fmaf(dp[8], rs2, 0.5f));      // svla
    float e0=ex2(x0*LOG2E), e1=ex2(x1*LOG2E), e2=ex2(x2*LOG2E);
    float e3=ex2(x3*LOG2E), e4=ex2(x4*LOG2E), e5=ex2(x5*LOG2E);
    float rs = rcpf_(e0+e1+e2+e3+e4+e5);
    nscr[er*6+0]=e0*rs; nscr[er*6+1]=e1*rs; nscr[er*6+2]=e2*rs;
    nscr[er*6+3]=e3*rs; nscr[er*6+4]=e4*rs; nscr[er*6+5]=e5*rs;
  }
  __syncthreads();   // (5) H6 + n2 ready; AS..VL dead -> reusable as fusion

  facc cc2[6][2];
  #pragma unroll
  for (int pr=0;pr<6;pr++){ facc z = {0,0,0,0}; cc2[pr][0]=z; cc2[pr][1]=z; }
  #pragma unroll
  for (int s=0;s<2;s++){
    int k=s*32+q*8;
    #pragma unroll
    for (int pr=0;pr<6;pr++){
      bfrag Af = *(const bfrag*)(smu + HH_E + pr*1152 + m*72 + k);
      cc2[pr][0] = MFMA(Af, C2[0][s], cc2[pr][0]);
      cc2[pr][1] = MFMA(Af, C2[1][s], cc2[pr][1]);
    }
  }
  { // trimodal -> LS_E; bim -> VS_E; uni -> AS_E   (fusion = [uni|bim|tri])
    float b2c0 = gf2_b2[w*16+m]*K2E, b2c1 = gf2_b2[(w+4)*16+m]*K2E;
    float tri[2][4] = {{0,0,0,0},{0,0,0,0}};
    float n2c[4][6];
    #pragma unroll
    for (int r=0;r<4;r++){
      #pragma unroll
      for (int j=0;j<6;j++) n2c[r][j] = nscr[(q*4+r)*6+j]*K2E;
    }
    #pragma unroll
    for (int pr=0;pr<6;pr++){
      #pragma unroll
      for (int t=0;t<2;t++){
        float bb = t? b2c1 : b2c0;
        #pragma unroll
        for (int r=0;r<4;r++){
          float g = ftanh_pre(fmaf(cc2[pr][t][r], K2E, bb));
          tri[t][r] += ftanh_pre(g*n2c[r][pr]);
        }
      }
    }
    #pragma unroll
    for (int t=0;t<2;t++){
      #pragma unroll
      for (int r=0;r<4;r++){
        smu[LS_E + (q*4+r)*136 + (w+4*t)*16+m] = f2b(tri[t][r]);
        smu[VS_E + (q*4+r)*136 + (w+4*t)*16+m] = f2b(bim[t][r]);
      }
    }
    *(uint2*)(smu + AS_E + er*136 + ep*4)      = make_uint2(uni_pk[0], uni_pk[1]);
    *(uint2*)(smu + AS_E + er*136 + ep*4 + 64) = make_uint2(uni_pk[2], uni_pk[3]);
  }
  __syncthreads();   // (6) fusion complete (AS|VS|LS), H6 consumed

  // ================= P4: final head 384->64->64->128 =================
  const u16* lw1 = wb + 49152;
  const u16* lw2 = wb + 73728;
  const u16* lw3 = wb + 77824;
  {
    facc c = {0,0,0,0};
    #pragma unroll
    for (int s=0;s<12;s++){
      const int base = (s<4)? AS_E : (s<8)? VS_E : LS_E;
      bfrag Bf = *(const bfrag*)(lw1 + (w*16+m)*384 + s*32 + q*8);
      bfrag Af = *(const bfrag*)(smu + base + m*136 + (s&3)*32 + q*8);
      c = MFMA(Af, Bf, c);
    }
    float bk = ll_b1[w*16+m]*K2E;
    #pragma unroll
    for (int r=0;r<4;r++)
      smu[HH_E + (q*4+r)*72 + w*16+m] = f2b(ftanh_pre(fmaf(c[r],K2E,bk)));
  }
  __syncthreads();   // (7)
  {
    facc c = {0,0,0,0};
    #pragma unroll
    for (int s=0;s<2;s++){
      bfrag Bf = *(const bfrag*)(lw2 + (w*16+m)*64 + s*32 + q*8);
      bfrag Af = *(const bfrag*)(smu + HH_E + m*72 + s*32 + q*8);
      c = MFMA(Af, Bf, c);
    }
    float bk = ll_b2[w*16+m]*K2E;
    #pragma unroll
    for (int r=0;r<4;r++)
      smu[HH_E + 1152 + (q*4+r)*72 + w*16+m] = f2b(ftanh_pre(fmaf(c[r],K2E,bk)));
  }
  __syncthreads();   // (8)
  {
    facc c0={0,0,0,0}, c1={0,0,0,0};
    #pragma unroll
    for (int s=0;s<2;s++){
      bfrag Af  = *(const bfrag*)(smu + HH_E + 1152 + m*72 + s*32 + q*8);
      bfrag Bf0 = *(const bfrag*)(lw3 + (w*16+m)*64 + s*32 + q*8);
      bfrag Bf1 = *(const bfrag*)(lw3 + ((w+4)*16+m)*64 + s*32 + q*8);
      c0 = MFMA(Af, Bf0, c0);
      c1 = MFMA(Af, Bf1, c1);
    }
    float b0k = ll_b3[w*16+m]*K2E, b1k = ll_b3[(w+4)*16+m]*K2E;
    #pragma unroll
    for (int r=0;r<4;r++){
      out[(row0+q*4+r)*128 + w*16+m]     = ftanh_pre(fmaf(c0[r],K2E,b0k));
      out[(row0+q*4+r)*128 + (w+4)*16+m] = ftanh_pre(fmaf(c1[r],K2E,b1k));
    }
  }
}

extern "C" void kernel_launch(void* const* d_in, const int* in_sizes, int n_in,
                              void* d_out, int out_size, void* d_ws, size_t ws_size,
                              hipStream_t stream)
{
  const float* l      = (const float*)d_in[0];
  const float* a      = (const float*)d_in[1];
  const float* v      = (const float*)d_in[2];
  const float* att_w  = (const float*)d_in[3];
  const float* att_b  = (const float*)d_in[4];
  const float* gf_w1  = (const float*)d_in[5];
  const float* gf_b1  = (const float*)d_in[6];
  const float* gf_w2  = (const float*)d_in[7];
  const float* gf_b2  = (const float*)d_in[8];
  const float* gf2_w1 = (const float*)d_in[9];
  const float* gf2_b1 = (const float*)d_in[10];
  const float* gf2_w2 = (const float*)d_in[11];
  const float* gf2_b2 = (const float*)d_in[12];
  const float* ll_w1  = (const float*)d_in[13];
  const float* ll_b1  = (const float*)d_in[14];
  const float* ll_w2  = (const float*)d_in[15];
  const float* ll_b2  = (const float*)d_in[16];
  const float* ll_w3  = (const float*)d_in[17];
  const float* ll_b3  = (const float*)d_in[18];
  u16* blob = (u16*)d_ws;

  prep_weights<<<336, 256, 0, stream>>>(gf_w1, gf_w2, gf2_w1, gf2_w2, ll_w1, ll_w2, ll_w3, blob);
  fused_graph<<<4096, 256, 0, stream>>>(l, a, v, att_w, att_b,
                                        gf_b1, gf_b2, gf2_b1, gf2_b2,
                                        ll_b1, ll_b2, ll_b3, blob, (float*)d_out);
}